// Round 4
// baseline (211.404 us; speedup 1.0000x reference)
//
#include <hip/hip_runtime.h>
#include <hip/hip_bf16.h>

#define N_SAMPLES 128
#define LAST_DIST 1e10f
#define EPS 1e-10f
#define RPW 4   // rays per wave

__device__ __forceinline__ float fast_sigmoid(float x) {
    // 1/(1+exp(-x)) via hw exp + hw rcp (~1 ulp each)
    return __builtin_amdgcn_rcpf(1.0f + __expf(-x));
}

// One 64-lane wave processes RPW consecutive rays. Lane l owns samples
// (l, 64+l) of each ray -> every global load is unit-stride across the wave.
// All shuffle-scan chains for the RPW rays are interleaved for ILP.
__global__ __launch_bounds__(256, 4) void render_rays_kernel(
    const float4* __restrict__ raw,   // [R * S] float4 (rgb + sigma)
    const float*  __restrict__ zv,    // [R * S] z_vals
    float* __restrict__ out,          // [R * 3]
    int n_rays)
{
    const int wave = threadIdx.x >> 6;
    const int lane = threadIdx.x & 63;
    const int r0 = (blockIdx.x * (blockDim.x >> 6) + wave) * RPW;
    if (r0 >= n_rays) return;

    // ---- batched loads: 8 x dwordx4 + 8 x dword issued up-front ----
    float4 fa[RPW], fb[RPW];
    float  za[RPW], zb[RPW];
    #pragma unroll
    for (int i = 0; i < RPW; ++i) {
        const int ri = (r0 + i < n_rays) ? (r0 + i) : (n_rays - 1);
        const size_t base = (size_t)ri * N_SAMPLES;
        fa[i] = raw[base + lane];
        fb[i] = raw[base + 64 + lane];
        za[i] = zv[base + lane];
        zb[i] = zv[base + 64 + lane];
    }

    // ---- dists, alpha-survival t = exp(-relu(sigma)*d) + eps ----
    float ea[RPW], eb[RPW], Pa[RPW], Pb[RPW];
    #pragma unroll
    for (int i = 0; i < RPW; ++i) {
        const float za_next = __shfl_down(za[i], 1);   // z[l+1]
        const float zb_next = __shfl_down(zb[i], 1);   // z[65+l]
        const float z64     = __shfl(zb[i], 0);        // z[64]
        const float da = ((lane == 63) ? z64 : za_next) - za[i];
        const float db = (lane == 63) ? LAST_DIST : (zb_next - zb[i]);
        ea[i] = __expf(-fmaxf(fa[i].w, 0.0f) * da);
        eb[i] = __expf(-fmaxf(fb[i].w, 0.0f) * db);
        Pa[i] = ea[i] + EPS;
        Pb[i] = eb[i] + EPS;
    }

    // ---- inclusive product scan, first half (samples 0..63), 4-way ILP ----
    #pragma unroll
    for (int off = 1; off < 64; off <<= 1) {
        float v[RPW];
        #pragma unroll
        for (int i = 0; i < RPW; ++i) v[i] = __shfl_up(Pa[i], off);
        #pragma unroll
        for (int i = 0; i < RPW; ++i) if (lane >= off) Pa[i] *= v[i];
    }
    float Ta[RPW], totA[RPW];
    #pragma unroll
    for (int i = 0; i < RPW; ++i) {
        Ta[i] = __shfl_up(Pa[i], 1);                   // exclusive
        if (lane == 0) Ta[i] = 1.0f;
        totA[i] = __shfl(Pa[i], 63);                   // prod of first-half t
    }

    // ---- inclusive product scan, second half (samples 64..127) ----
    #pragma unroll
    for (int off = 1; off < 64; off <<= 1) {
        float v[RPW];
        #pragma unroll
        for (int i = 0; i < RPW; ++i) v[i] = __shfl_up(Pb[i], off);
        #pragma unroll
        for (int i = 0; i < RPW; ++i) if (lane >= off) Pb[i] *= v[i];
    }
    float Tb[RPW];
    #pragma unroll
    for (int i = 0; i < RPW; ++i) {
        Tb[i] = __shfl_up(Pb[i], 1);
        if (lane == 0) Tb[i] = 1.0f;
        Tb[i] *= totA[i];
    }

    // ---- weights & per-lane weighted color ----
    float acc[RPW][3];
    #pragma unroll
    for (int i = 0; i < RPW; ++i) {
        const float wa = (1.0f - ea[i]) * Ta[i];
        const float wb = (1.0f - eb[i]) * Tb[i];
        acc[i][0] = wa * fast_sigmoid(fa[i].x) + wb * fast_sigmoid(fb[i].x);
        acc[i][1] = wa * fast_sigmoid(fa[i].y) + wb * fast_sigmoid(fb[i].y);
        acc[i][2] = wa * fast_sigmoid(fa[i].z) + wb * fast_sigmoid(fb[i].z);
    }

    // ---- wave reduction: 12 independent butterfly chains, interleaved ----
    #pragma unroll
    for (int off = 32; off > 0; off >>= 1) {
        #pragma unroll
        for (int i = 0; i < RPW; ++i) {
            #pragma unroll
            for (int c = 0; c < 3; ++c)
                acc[i][c] += __shfl_xor(acc[i][c], off);
        }
    }

    // ---- stores: 4 lanes each write one ray's 3 floats ----
    #pragma unroll
    for (int i = 0; i < RPW; ++i) {
        if (lane == i * 16 && (r0 + i) < n_rays) {
            const size_t o = (size_t)(r0 + i) * 3;
            out[o + 0] = acc[i][0];
            out[o + 1] = acc[i][1];
            out[o + 2] = acc[i][2];
        }
    }
}

extern "C" void kernel_launch(void* const* d_in, const int* in_sizes, int n_in,
                              void* d_out, int out_size, void* d_ws, size_t ws_size,
                              hipStream_t stream) {
    const float4* raw = (const float4*)d_in[0];       // [R, S, 4] f32
    const float*  zv  = (const float*)d_in[1];        // [R, S]   f32
    float* out        = (float*)d_out;                // [R, 3]   f32

    const int n_rays = in_sizes[0] / (N_SAMPLES * 4);

    const int waves_per_block = 4;                    // 256 threads
    const int block = waves_per_block * 64;
    const int rays_per_block = waves_per_block * RPW; // 16
    const int grid = (n_rays + rays_per_block - 1) / rays_per_block;

    render_rays_kernel<<<grid, block, 0, stream>>>(raw, zv, out, n_rays);
}